// Round 6
// baseline (267.015 us; speedup 1.0000x reference)
//
#include <hip/hip_runtime.h>
#include <hip/hip_bf16.h>
#include <math.h>

#define NTOK 4096
#define DMODEL 1024
#define DHID 2048
#define NEXP 8
#define CAP 640

typedef __attribute__((ext_vector_type(8))) short short8;
typedef __attribute__((ext_vector_type(4))) float f32x4;

__device__ inline short f2bf(float f) {
    union { float f; unsigned u; } v; v.f = f;
    unsigned r = v.u + 0x7FFF + ((v.u >> 16) & 1);   // RNE (inputs are finite)
    return (short)(r >> 16);
}
__device__ inline float bf2f(unsigned short u) {
    union { unsigned u; float f; } v; v.u = ((unsigned)u) << 16; return v.f;
}
__device__ inline void async16(const short* g, short* l) {
    __builtin_amdgcn_global_load_lds(
        (const __attribute__((address_space(1))) unsigned*)g,
        (__attribute__((address_space(3))) unsigned*)l, 16, 0, 0);
}

// ---------------- Router: logits -> softmax -> top2 (fp32) + x -> bf16 ----------------
__global__ __launch_bounds__(256) void router_kernel(
        const float* __restrict__ x, const float* __restrict__ wr, short* __restrict__ Xb,
        int2* __restrict__ topk_idx, float2* __restrict__ topk_gate)
{
    const int token = blockIdx.x * 4 + (threadIdx.x >> 6);
    const int lane  = threadIdx.x & 63;
    const float* xr = x + (size_t)token * DMODEL + lane * 16;
    float4 xv[4];
#pragma unroll
    for (int j = 0; j < 4; j++) xv[j] = ((const float4*)xr)[j];
    short8 s0 = { f2bf(xv[0].x), f2bf(xv[0].y), f2bf(xv[0].z), f2bf(xv[0].w),
                  f2bf(xv[1].x), f2bf(xv[1].y), f2bf(xv[1].z), f2bf(xv[1].w) };
    short8 s1 = { f2bf(xv[2].x), f2bf(xv[2].y), f2bf(xv[2].z), f2bf(xv[2].w),
                  f2bf(xv[3].x), f2bf(xv[3].y), f2bf(xv[3].z), f2bf(xv[3].w) };
    short* xo = Xb + (size_t)token * DMODEL + lane * 16;
    *(short8*)xo = s0;
    *(short8*)(xo + 8) = s1;

    float acc[NEXP];
#pragma unroll
    for (int e = 0; e < NEXP; e++) acc[e] = 0.f;
#pragma unroll
    for (int j = 0; j < 4; j++) {
#pragma unroll
        for (int e = 0; e < NEXP; e++) {
            float4 wv = ((const float4*)(wr + e * DMODEL + lane * 16))[j];
            acc[e] += xv[j].x * wv.x + xv[j].y * wv.y + xv[j].z * wv.z + xv[j].w * wv.w;
        }
    }
#pragma unroll
    for (int off = 32; off >= 1; off >>= 1) {
#pragma unroll
        for (int e = 0; e < NEXP; e++) acc[e] += __shfl_xor(acc[e], off, 64);
    }
    if (lane == 0) {
        float m = acc[0];
#pragma unroll
        for (int e = 1; e < NEXP; e++) m = fmaxf(m, acc[e]);
        float den = 0.f, g[NEXP];
#pragma unroll
        for (int e = 0; e < NEXP; e++) { g[e] = __expf(acc[e] - m); den += g[e]; }
        float inv = 1.f / den;
#pragma unroll
        for (int e = 0; e < NEXP; e++) g[e] *= inv;
        int i0 = 0; float l0 = acc[0];
#pragma unroll
        for (int e = 1; e < NEXP; e++) if (acc[e] > l0) { l0 = acc[e]; i0 = e; }
        int i1 = -1; float l1 = -1e30f;
#pragma unroll
        for (int e = 0; e < NEXP; e++) if (e != i0 && acc[e] > l1) { l1 = acc[e]; i1 = e; }
        topk_idx[token]  = make_int2(i0, i1);
        topk_gate[token] = make_float2(g[i0], g[i1]);
    }
}

// legacy router (fallback path, no Xb)
__global__ __launch_bounds__(256) void router_fb_kernel(
        const float* __restrict__ x, const float* __restrict__ wr,
        int2* __restrict__ topk_idx, float2* __restrict__ topk_gate)
{
    const int token = blockIdx.x * 4 + (threadIdx.x >> 6);
    const int lane  = threadIdx.x & 63;
    const float* xr = x + (size_t)token * DMODEL + lane * 16;
    float acc[NEXP];
#pragma unroll
    for (int e = 0; e < NEXP; e++) acc[e] = 0.f;
#pragma unroll
    for (int j = 0; j < 4; j++) {
        float4 xv = ((const float4*)xr)[j];
#pragma unroll
        for (int e = 0; e < NEXP; e++) {
            float4 wv = ((const float4*)(wr + e * DMODEL + lane * 16))[j];
            acc[e] += xv.x * wv.x + xv.y * wv.y + xv.z * wv.z + xv.w * wv.w;
        }
    }
#pragma unroll
    for (int off = 32; off >= 1; off >>= 1) {
#pragma unroll
        for (int e = 0; e < NEXP; e++) acc[e] += __shfl_xor(acc[e], off, 64);
    }
    if (lane == 0) {
        float m = acc[0];
#pragma unroll
        for (int e = 1; e < NEXP; e++) m = fmaxf(m, acc[e]);
        float den = 0.f, g[NEXP];
#pragma unroll
        for (int e = 0; e < NEXP; e++) { g[e] = __expf(acc[e] - m); den += g[e]; }
        float inv = 1.f / den;
#pragma unroll
        for (int e = 0; e < NEXP; e++) g[e] *= inv;
        int i0 = 0; float l0 = acc[0];
#pragma unroll
        for (int e = 1; e < NEXP; e++) if (acc[e] > l0) { l0 = acc[e]; i0 = e; }
        int i1 = -1; float l1 = -1e30f;
#pragma unroll
        for (int e = 0; e < NEXP; e++) if (e != i0 && acc[e] > l1) { l1 = acc[e]; i1 = e; }
        topk_idx[token]  = make_int2(i0, i1);
        topk_gate[token] = make_float2(g[i0], g[i1]);
    }
}

// ---------------- fp32 -> bf16 conversion: two arrays in one dispatch ----------------
__global__ __launch_bounds__(256) void convert2_kernel(
        const float* __restrict__ a, short* __restrict__ da, size_t na,
        const float* __restrict__ b, short* __restrict__ db)
{
    size_t i = ((size_t)blockIdx.x * 256 + threadIdx.x) * 8;
    const float* src; short* dst;
    if (i < na) { src = a + i; dst = da + i; }
    else        { src = b + (i - na); dst = db + (i - na); }
    float4 v0 = ((const float4*)src)[0];
    float4 v1 = ((const float4*)src)[1];
    short8 s = { f2bf(v0.x), f2bf(v0.y), f2bf(v0.z), f2bf(v0.w),
                 f2bf(v1.x), f2bf(v1.y), f2bf(v1.z), f2bf(v1.w) };
    *(short8*)dst = s;
}

// ---------------- Capacity scan + gather/combine metadata (exact cumsum) ------------
__global__ __launch_bounds__(1024) void scan_kernel(
        const int2* __restrict__ topk_idx, const float2* __restrict__ topk_gate,
        int* __restrict__ gtok, float* __restrict__ gw, int* __restrict__ gcnt,
        int2* __restrict__ tslot, float2* __restrict__ tw)
{
    __shared__ unsigned long long wt0[16], wt1[16];
    const int th = threadIdx.x, lane = th & 63, wid = th >> 6;
    int2 idx[4]; float2 gt[4];
#pragma unroll
    for (int j = 0; j < 4; j++) { idx[j] = topk_idx[th * 4 + j]; gt[j] = topk_gate[th * 4 + j]; }
    unsigned long long c0 = 0, c1 = 0;   // experts 0-3 / 4-7, 16-bit fields
#pragma unroll
    for (int j = 0; j < 4; j++) {
        int e0 = idx[j].x, e1 = idx[j].y;
        if (e0 < 4) c0 += 1ull << (e0 * 16); else c1 += 1ull << ((e0 - 4) * 16);
        if (e1 < 4) c0 += 1ull << (e1 * 16); else c1 += 1ull << ((e1 - 4) * 16);
    }
    const unsigned long long my0 = c0, my1 = c1;
#pragma unroll
    for (int d = 1; d < 64; d <<= 1) {
        unsigned long long t0 = __shfl_up(c0, d, 64);
        unsigned long long t1 = __shfl_up(c1, d, 64);
        if (lane >= d) { c0 += t0; c1 += t1; }
    }
    if (lane == 63) { wt0[wid] = c0; wt1[wid] = c1; }
    __syncthreads();
    unsigned long long o0 = 0, o1 = 0;
    for (int w = 0; w < wid; w++) { o0 += wt0[w]; o1 += wt1[w]; }
    c0 += o0; c1 += o1;
    if (th == 1023) {
#pragma unroll
        for (int e = 0; e < 4; e++) gcnt[e]     = min((int)((c0 >> (e * 16)) & 0xFFFF), CAP);
#pragma unroll
        for (int e = 0; e < 4; e++) gcnt[4 + e] = min((int)((c1 >> (e * 16)) & 0xFFFF), CAP);
    }
    const unsigned long long x0 = c0 - my0, x1 = c1 - my1;  // exclusive
    int base[NEXP];
#pragma unroll
    for (int e = 0; e < 4; e++) base[e]     = (int)((x0 >> (e * 16)) & 0xFFFF);
#pragma unroll
    for (int e = 0; e < 4; e++) base[4 + e] = (int)((x1 >> (e * 16)) & 0xFFFF);
#pragma unroll
    for (int j = 0; j < 4; j++) {
        const int n = th * 4 + j;
        const int e0 = idx[j].x, e1 = idx[j].y;
        const int p0 = base[e0]++;
        const int p1 = base[e1]++;
        const bool k0 = p0 < CAP, k1 = p1 < CAP;
        const float gg0 = k0 ? gt[j].x : 0.f, gg1 = k1 ? gt[j].y : 0.f;
        const float invs = 1.f / (gg0 + gg1 + 1e-6f);
        const int s0 = k0 ? e0 * CAP + p0 : 0;
        const int s1 = k1 ? e1 * CAP + p1 : 0;
        if (k0) { gtok[s0] = n; gw[s0] = gg0 * invs; }
        if (k1) { gtok[s1] = n; gw[s1] = gg1 * invs; }
        tslot[n] = make_int2(s0, s1);
        tw[n]    = make_float2(gg0 * invs, gg1 * invs);
    }
}

// ---------------- GEMM1 (2-wave blocks, 128x64 tile): hidden = silu(Xb @ WGb^T) -----
// Per-wave MFMA density identical to the 128x128/4-wave version (4x4 frags, 32 MFMA
// per barrier-pair), but blocks are half the waves and 24 KB LDS -> multiple
// independent blocks co-reside per CU, so one block's MFMA covers another's staging
// (m114 mechanism). Fragment-ordered LDS: block b = row16*2 + colhalf, 1 KB each;
// wave reads are 64 consecutive 16B chunks -> 0 bank conflicts, matches
// global_load_lds lane order. Grid 32x32 = 1024 blocks = 4/CU.
__global__ __launch_bounds__(128) void gemm1_kernel(
        const short* __restrict__ Xb, const short* __restrict__ WGb, short* __restrict__ Hid)
{
    __shared__ __align__(16) short As[128 * 64];   // 16 KB, 16 fragment blocks
    __shared__ __align__(16) short Bs[64 * 64];    // 8 KB, 8 fragment blocks
    const int t = threadIdx.x;
    const int wave = t >> 6, lane = t & 63;
    const int m0 = blockIdx.y * 128, n0 = blockIdx.x * 64;
    const int lm = lane & 15, lq = lane >> 4;

    // staging map: chunk c = j*128 + t; c in [0,1024) -> A, [1024,1536) -> B
    const short *ga[12]; short* la[12];
#pragma unroll
    for (int j = 0; j < 12; j++) {
        const int c = j * 128 + t;
        if (c < 1024) {
            const int b = c >> 6, l = c & 63;
            const int row = (b >> 1) * 16 + (l & 15);
            const int col = (b & 1) * 32 + (l >> 4) * 8;
            la[j] = &As[c * 8];
            ga[j] = Xb + (size_t)(m0 + row) * DMODEL + col;
        } else {
            const int cb = c - 1024;
            const int b = cb >> 6, l = cb & 63;
            const int row = (b >> 1) * 16 + (l & 15);
            const int col = (b & 1) * 32 + (l >> 4) * 8;
            la[j] = &Bs[cb * 8];
            ga[j] = WGb + (size_t)(n0 + row) * DMODEL + col;
        }
    }

    f32x4 acc[4][4];
#pragma unroll
    for (int a = 0; a < 4; a++)
#pragma unroll
        for (int b = 0; b < 4; b++) acc[a][b] = (f32x4)(0.f);

    for (int k0 = 0; k0 < DMODEL; k0 += 64) {
#pragma unroll
        for (int j = 0; j < 12; j++) async16(ga[j] + k0, la[j]);
        __syncthreads();
#pragma unroll
        for (int kk = 0; kk < 2; kk++) {
            short8 af[4], bf[4];
#pragma unroll
            for (int mi = 0; mi < 4; mi++)
                af[mi] = *(const short8*)&As[(((wave * 4 + mi) * 2 + kk) * 64 + lane) * 8];
#pragma unroll
            for (int ni = 0; ni < 4; ni++)
                bf[ni] = *(const short8*)&Bs[((ni * 2 + kk) * 64 + lane) * 8];
#pragma unroll
            for (int mi = 0; mi < 4; mi++)
#pragma unroll
                for (int ni = 0; ni < 4; ni++)
                    acc[mi][ni] = __builtin_amdgcn_mfma_f32_16x16x32_bf16(af[mi], bf[ni], acc[mi][ni], 0, 0, 0);
        }
        __syncthreads();
    }
#pragma unroll
    for (int mi = 0; mi < 4; mi++)
#pragma unroll
        for (int i = 0; i < 4; i++) {
            const int row = m0 + wave * 64 + mi * 16 + lq * 4 + i;
#pragma unroll
            for (int ni = 0; ni < 4; ni++) {
                const int col = n0 + ni * 16 + lm;
                const float v = acc[mi][ni][i];
                const float s = v / (1.f + __expf(-v));
                Hid[(size_t)row * DHID + col] = f2bf(s);
            }
        }
}

// ---------------- GEMM2 (2-wave blocks, 128x64 tile, no atomics): Yp[slot] = A@B^T --
// Grid 8 x 16 x 5 = 640 blocks = 2.5/CU; blockIdx.x = expert -> XCD L2 pinning.
__global__ __launch_bounds__(128) void gemm2_kernel(
        const short* __restrict__ Hid, const short* __restrict__ WDb,
        const int* __restrict__ gtok, const int* __restrict__ gcnt,
        short* __restrict__ Yp)
{
    __shared__ __align__(16) short As[128 * 64];   // 16 KB
    __shared__ __align__(16) short Bs[64 * 64];    // 8 KB
    __shared__ int tok_s[128];
    const int e  = blockIdx.x;
    const int n0 = blockIdx.y * 64;
    const int m0 = blockIdx.z * 128;
    const int cnt = gcnt[e];
    if (m0 >= cnt) return;
    const int t = threadIdx.x;
    const int wave = t >> 6, lane = t & 63;
    const int lm = lane & 15, lq = lane >> 4;
    const short* WDe = WDb + (size_t)e * DMODEL * DHID;

    tok_s[t] = (m0 + t < cnt) ? gtok[e * CAP + m0 + t] : 0;
    __syncthreads();

    const short *ga[12]; short* la[12];
#pragma unroll
    for (int j = 0; j < 12; j++) {
        const int c = j * 128 + t;
        if (c < 1024) {
            const int b = c >> 6, l = c & 63;
            const int row = (b >> 1) * 16 + (l & 15);
            const int col = (b & 1) * 32 + (l >> 4) * 8;
            la[j] = &As[c * 8];
            ga[j] = Hid + (size_t)tok_s[row] * DHID + col;
        } else {
            const int cb = c - 1024;
            const int b = cb >> 6, l = cb & 63;
            const int row = (b >> 1) * 16 + (l & 15);
            const int col = (b & 1) * 32 + (l >> 4) * 8;
            la[j] = &Bs[cb * 8];
            ga[j] = WDe + (size_t)(n0 + row) * DHID + col;
        }
    }

    f32x4 acc[4][4];
#pragma unroll
    for (int a = 0; a < 4; a++)
#pragma unroll
        for (int b = 0; b < 4; b++) acc[a][b] = (f32x4)(0.f);

    for (int k0 = 0; k0 < DHID; k0 += 64) {
#pragma unroll
        for (int j = 0; j < 12; j++) async16(ga[j] + k0, la[j]);
        __syncthreads();
#pragma unroll
        for (int kk = 0; kk < 2; kk++) {
            short8 af[4], bf[4];
#pragma unroll
            for (int mi = 0; mi < 4; mi++)
                af[mi] = *(const short8*)&As[(((wave * 4 + mi) * 2 + kk) * 64 + lane) * 8];
#pragma unroll
            for (int ni = 0; ni < 4; ni++)
                bf[ni] = *(const short8*)&Bs[((ni * 2 + kk) * 64 + lane) * 8];
#pragma unroll
            for (int mi = 0; mi < 4; mi++)
#pragma unroll
                for (int ni = 0; ni < 4; ni++)
                    acc[mi][ni] = __builtin_amdgcn_mfma_f32_16x16x32_bf16(af[mi], bf[ni], acc[mi][ni], 0, 0, 0);
        }
        __syncthreads();
    }
    // plain bf16 stores; gate weight applied in combine
#pragma unroll
    for (int mi = 0; mi < 4; mi++)
#pragma unroll
        for (int i = 0; i < 4; i++) {
            const int slot = e * CAP + m0 + wave * 64 + mi * 16 + lq * 4 + i;
#pragma unroll
            for (int ni = 0; ni < 4; ni++) {
                const int col = n0 + ni * 16 + lm;
                Yp[(size_t)slot * DMODEL + col] = f2bf(acc[mi][ni][i]);
            }
        }
}

// ---------------- Combine: y[n] = w0*Yp[s0] + w1*Yp[s1] ----------------
__global__ __launch_bounds__(256) void combine_kernel(
        const short* __restrict__ Yp, const int2* __restrict__ tslot,
        const float2* __restrict__ tw, float* __restrict__ y)
{
    const int token = blockIdx.x;
    const int c = threadIdx.x * 4;
    const int2   s = tslot[token];
    const float2 w = tw[token];
    ushort4 a = *(const ushort4*)((const unsigned short*)Yp + (size_t)s.x * DMODEL + c);
    ushort4 b = *(const ushort4*)((const unsigned short*)Yp + (size_t)s.y * DMODEL + c);
    float4 o;
    o.x = w.x * bf2f(a.x) + w.y * bf2f(b.x);
    o.y = w.x * bf2f(a.y) + w.y * bf2f(b.y);
    o.z = w.x * bf2f(a.z) + w.y * bf2f(b.z);
    o.w = w.x * bf2f(a.w) + w.y * bf2f(b.w);
    *(float4*)&y[(size_t)token * DMODEL + c] = o;
}

// ---------------- Fallback GEMMs (round-0 proven, fp32 inline-convert) ----------------
__global__ __launch_bounds__(256) void gemm1_fb_kernel(
        const float* __restrict__ X, const float* __restrict__ WG, short* __restrict__ Hid)
{
    __shared__ short As[128][72];
    __shared__ short Bs[128][72];
    const int t = threadIdx.x;
    const int wave = t >> 6, lane = t & 63;
    const int m0 = blockIdx.y * 128, n0 = blockIdx.x * 128;
    const int wm = (wave >> 1) * 64, wn = (wave & 1) * 64;
    const int lm = lane & 15, lq = lane >> 4, lk = lq * 8;
    const int r0 = t >> 3, c8 = (t & 7) * 8;

    f32x4 acc[4][4];
#pragma unroll
    for (int a = 0; a < 4; a++)
#pragma unroll
        for (int b = 0; b < 4; b++) acc[a][b] = (f32x4)(0.f);

    for (int k0 = 0; k0 < DMODEL; k0 += 64) {
#pragma unroll
        for (int i = 0; i < 4; i++) {
            const int row = r0 + i * 32;
            const float* ga = X + (size_t)(m0 + row) * DMODEL + k0 + c8;
            float4 v0 = ((const float4*)ga)[0];
            float4 v1 = ((const float4*)ga)[1];
            short8 s = { f2bf(v0.x), f2bf(v0.y), f2bf(v0.z), f2bf(v0.w),
                         f2bf(v1.x), f2bf(v1.y), f2bf(v1.z), f2bf(v1.w) };
            *(short8*)&As[row][c8] = s;
            const float* gb = WG + (size_t)(n0 + row) * DMODEL + k0 + c8;
            float4 w0 = ((const float4*)gb)[0];
            float4 w1 = ((const float4*)gb)[1];
            short8 sw = { f2bf(w0.x), f2bf(w0.y), f2bf(w0.z), f2bf(w0.w),
                          f2bf(w1.x), f2bf(w1.y), f2bf(w1.z), f2bf(w1.w) };
            *(short8*)&Bs[row][c8] = sw;
        }
        __syncthreads();
#pragma unroll
        for (int kk = 0; kk < 64; kk += 32) {
            short8 af[4], bf[4];
#pragma unroll
            for (int mi = 0; mi < 4; mi++) af[mi] = *(const short8*)&As[wm + mi * 16 + lm][kk + lk];
#pragma unroll
            for (int ni = 0; ni < 4; ni++) bf[ni] = *(const short8*)&Bs[wn + ni * 16 + lm][kk + lk];
#pragma unroll
            for (int mi = 0; mi < 4; mi++)
#pragma unroll
                for (int ni = 0; ni < 4; ni++)
                    acc[mi][ni] = __builtin_amdgcn_mfma_f32_16x16x32_bf16(af[mi], bf[ni], acc[mi][ni], 0, 0, 0);
        }
        __syncthreads();
    }
#pragma unroll
    for (int mi = 0; mi < 4; mi++)
#pragma unroll
        for (int i = 0; i < 4; i++) {
            const int row = m0 + wm + mi * 16 + lq * 4 + i;
#pragma unroll
            for (int ni = 0; ni < 4; ni++) {
                const int col = n0 + wn + ni * 16 + lm;
                const float v = acc[mi][ni][i];
                const float s = v / (1.f + __expf(-v));
                Hid[(size_t)row * DHID + col] = f2bf(s);
            }
        }
}

__global__ __launch_bounds__(256) void gemm2_fb_kernel(
        const short* __restrict__ Hid, const float* __restrict__ WD,
        const int* __restrict__ gtok, const float* __restrict__ gw,
        const int* __restrict__ gcnt, float* __restrict__ Y)
{
    __shared__ short As[128][72];
    __shared__ short Bs[128][72];
    __shared__ int   tok_s[128];
    __shared__ float w_s[128];
    const int e = blockIdx.z;
    const int cnt = gcnt[e];
    const int m0 = blockIdx.y * 128;
    if (m0 >= cnt) return;
    const int n0 = blockIdx.x * 128;
    const int t = threadIdx.x;
    const int wave = t >> 6, lane = t & 63;
    const int wm = (wave >> 1) * 64, wn = (wave & 1) * 64;
    const int lm = lane & 15, lq = lane >> 4, lk = lq * 8;
    const int r0 = t >> 3, c8 = (t & 7) * 8;
    const float* WDe = WD + (size_t)e * DMODEL * DHID;

    if (t < 128) {
        const int r = m0 + t;
        const bool v = r < cnt;
        tok_s[t] = v ? gtok[e * CAP + r] : 0;
        w_s[t]   = v ? gw[e * CAP + r] : 0.f;
    }
    __syncthreads();

    f32x4 acc[4][4];
#pragma unroll
    for (int a = 0; a < 4; a++)
#pragma unroll
        for (int b = 0; b < 4; b++) acc[a][b] = (f32x4)(0.f);

    const int tokA[4] = { tok_s[r0], tok_s[r0 + 32], tok_s[r0 + 64], tok_s[r0 + 96] };

    for (int k0 = 0; k0 < DHID; k0 += 64) {
#pragma unroll
        for (int i = 0; i < 4; i++) {
            const int row = r0 + i * 32;
            uint4 av = *(const uint4*)(Hid + (size_t)tokA[i] * DHID + k0 + c8);
            *(uint4*)&As[row][c8] = av;
            const float* gb = WDe + (size_t)(n0 + row) * DHID + k0 + c8;
            float4 w0 = ((const float4*)gb)[0];
            float4 w1 = ((const float4*)gb)[1];
            short8 sw = { f2bf(w0.x), f2bf(w0.y), f2bf(w0.z), f2bf(w0.w),
                          f2bf(w1.x), f2bf(w1.y), f2bf(w1.z), f2bf(w1.w) };
            *(short8*)&Bs[row][c8] = sw;
        }
        __syncthreads();
#pragma unroll
        for (int kk = 0; kk < 64; kk += 32) {
            short8 af[4], bf[4];
#pragma unroll
            for (int mi = 0; mi < 4; mi++) af[mi] = *(const short8*)&As[wm + mi * 16 + lm][kk + lk];
#pragma unroll
            for (int ni = 0; ni < 4; ni++) bf[ni] = *(const short8*)&Bs[wn + ni * 16 + lm][kk + lk];
#pragma unroll
            for (int mi = 0; mi < 4; mi++)
#pragma unroll
                for (int ni = 0; ni < 4; ni++)
                    acc[mi][ni] = __builtin_amdgcn_mfma_f32_16x16x32_bf16(af[mi], bf[ni], acc[mi][ni], 0, 0, 0);
        }
        __syncthreads();
    }
#pragma unroll
    for (int mi = 0; mi < 4; mi++)
#pragma unroll
        for (int i = 0; i < 4; i++) {
            const int r = wm + mi * 16 + lq * 4 + i;
            const float wr = w_s[r];
            if (wr > 0.f) {
                const int token = tok_s[r];
#pragma unroll
                for (int ni = 0; ni < 4; ni++) {
                    const int col = n0 + wn + ni * 16 + lm;
                    atomicAdd(&Y[(size_t)token * DMODEL + col], acc[mi][ni][i] * wr);
                }
            }
        }
}

extern "C" void kernel_launch(void* const* d_in, const int* in_sizes, int n_in,
                              void* d_out, int out_size, void* d_ws, size_t ws_size,
                              hipStream_t stream) {
    const float* x  = (const float*)d_in[0];
    const float* wr = (const float*)d_in[1];
    const float* wg = (const float*)d_in[2];
    const float* wd = (const float*)d_in[3];
    float* y = (float*)d_out;

    char* w = (char*)d_ws;
    int2*   topk_idx  = (int2*)w;    w += NTOK * sizeof(int2);
    float2* topk_gate = (float2*)w;  w += NTOK * sizeof(float2);
    int*    gtok      = (int*)w;     w += NEXP * CAP * sizeof(int);
    float*  gw        = (float*)w;   w += NEXP * CAP * sizeof(float);
    int*    gcnt      = (int*)w;     w += 256;
    int2*   tslot     = (int2*)w;    w += NTOK * sizeof(int2);
    float2* tw        = (float2*)w;  w += NTOK * sizeof(float2);
    short*  Hid       = (short*)w;   w += (size_t)NTOK * DHID * sizeof(short);
    short*  WDb       = (short*)w;   w += (size_t)NEXP * DMODEL * DHID * sizeof(short);
    // Xb and WGb are dead after gemm1 completes; Yp (8*640*1024 bf16 = 10.5 MB)
    // aliases their 12.6 MB region so the total stays ~63 MB.
    short*  Xb        = (short*)w;   // 8 MB
    short*  WGb       = (short*)(w + (size_t)NTOK * DMODEL * sizeof(short));  // 4 MB
    short*  Yp        = (short*)w;
    w += (size_t)NTOK * DMODEL * sizeof(short) + (size_t)DHID * DMODEL * sizeof(short);
    const size_t need_full = (size_t)(w - (char*)d_ws);

    if (ws_size >= need_full) {
        router_kernel<<<NTOK / 4, 256, 0, stream>>>(x, wr, Xb, topk_idx, topk_gate);
        convert2_kernel<<<(DHID * DMODEL + NEXP * DMODEL * DHID) / (256 * 8), 256, 0, stream>>>(
            wg, WGb, (size_t)DHID * DMODEL, wd, WDb);
        scan_kernel<<<1, 1024, 0, stream>>>(topk_idx, topk_gate, gtok, gw, gcnt, tslot, tw);
        gemm1_kernel<<<dim3(DHID / 64, NTOK / 128), 128, 0, stream>>>(Xb, WGb, Hid);
        gemm2_kernel<<<dim3(NEXP, DMODEL / 64, CAP / 128), 128, 0, stream>>>(
            Hid, WDb, gtok, gcnt, Yp);
        combine_kernel<<<NTOK, 256, 0, stream>>>(Yp, tslot, tw, y);
    } else {
        hipMemsetAsync(y, 0, (size_t)NTOK * DMODEL * sizeof(float), stream);
        router_fb_kernel<<<NTOK / 4, 256, 0, stream>>>(x, wr, topk_idx, topk_gate);
        scan_kernel<<<1, 1024, 0, stream>>>(topk_idx, topk_gate, gtok, gw, gcnt, tslot, tw);
        gemm1_fb_kernel<<<dim3(DHID / 128, NTOK / 128), 256, 0, stream>>>(x, wg, Hid);
        gemm2_fb_kernel<<<dim3(DMODEL / 128, (CAP + 127) / 128, NEXP), 256, 0, stream>>>(
            Hid, wd, gtok, gw, gcnt, y);
    }
}

// Round 7
// 249.068 us; speedup vs baseline: 1.0721x; 1.0721x over previous
//
#include <hip/hip_runtime.h>
#include <hip/hip_bf16.h>
#include <math.h>

#define NTOK 4096
#define DMODEL 1024
#define DHID 2048
#define NEXP 8
#define CAP 640
#define SLOTS (NEXP * CAP)

typedef __attribute__((ext_vector_type(8))) short short8;
typedef __attribute__((ext_vector_type(4))) float f32x4;

__device__ inline short f2bf(float f) {
    union { float f; unsigned u; } v; v.f = f;
    unsigned r = v.u + 0x7FFF + ((v.u >> 16) & 1);   // RNE (inputs are finite)
    return (short)(r >> 16);
}
__device__ inline float bf2f(unsigned short u) {
    union { unsigned u; float f; } v; v.u = ((unsigned)u) << 16; return v.f;
}
__device__ inline void async16(const short* g, short* l) {
    __builtin_amdgcn_global_load_lds(
        (const __attribute__((address_space(1))) unsigned*)g,
        (__attribute__((address_space(3))) unsigned*)l, 16, 0, 0);
}

// ---------------- Router: logits -> softmax -> top2 (fp32) + x -> bf16 ----------------
__global__ __launch_bounds__(256) void router_kernel(
        const float* __restrict__ x, const float* __restrict__ wr, short* __restrict__ Xb,
        int2* __restrict__ topk_idx, float2* __restrict__ topk_gate)
{
    const int token = blockIdx.x * 4 + (threadIdx.x >> 6);
    const int lane  = threadIdx.x & 63;
    const float* xr = x + (size_t)token * DMODEL + lane * 16;
    float4 xv[4];
#pragma unroll
    for (int j = 0; j < 4; j++) xv[j] = ((const float4*)xr)[j];
    short8 s0 = { f2bf(xv[0].x), f2bf(xv[0].y), f2bf(xv[0].z), f2bf(xv[0].w),
                  f2bf(xv[1].x), f2bf(xv[1].y), f2bf(xv[1].z), f2bf(xv[1].w) };
    short8 s1 = { f2bf(xv[2].x), f2bf(xv[2].y), f2bf(xv[2].z), f2bf(xv[2].w),
                  f2bf(xv[3].x), f2bf(xv[3].y), f2bf(xv[3].z), f2bf(xv[3].w) };
    short* xo = Xb + (size_t)token * DMODEL + lane * 16;
    *(short8*)xo = s0;
    *(short8*)(xo + 8) = s1;

    float acc[NEXP];
#pragma unroll
    for (int e = 0; e < NEXP; e++) acc[e] = 0.f;
#pragma unroll
    for (int j = 0; j < 4; j++) {
#pragma unroll
        for (int e = 0; e < NEXP; e++) {
            float4 wv = ((const float4*)(wr + e * DMODEL + lane * 16))[j];
            acc[e] += xv[j].x * wv.x + xv[j].y * wv.y + xv[j].z * wv.z + xv[j].w * wv.w;
        }
    }
#pragma unroll
    for (int off = 32; off >= 1; off >>= 1) {
#pragma unroll
        for (int e = 0; e < NEXP; e++) acc[e] += __shfl_xor(acc[e], off, 64);
    }
    if (lane == 0) {
        float m = acc[0];
#pragma unroll
        for (int e = 1; e < NEXP; e++) m = fmaxf(m, acc[e]);
        float den = 0.f, g[NEXP];
#pragma unroll
        for (int e = 0; e < NEXP; e++) { g[e] = __expf(acc[e] - m); den += g[e]; }
        float inv = 1.f / den;
#pragma unroll
        for (int e = 0; e < NEXP; e++) g[e] *= inv;
        int i0 = 0; float l0 = acc[0];
#pragma unroll
        for (int e = 1; e < NEXP; e++) if (acc[e] > l0) { l0 = acc[e]; i0 = e; }
        int i1 = -1; float l1 = -1e30f;
#pragma unroll
        for (int e = 0; e < NEXP; e++) if (e != i0 && acc[e] > l1) { l1 = acc[e]; i1 = e; }
        topk_idx[token]  = make_int2(i0, i1);
        topk_gate[token] = make_float2(g[i0], g[i1]);
    }
}

// legacy router (fallback path, no Xb)
__global__ __launch_bounds__(256) void router_fb_kernel(
        const float* __restrict__ x, const float* __restrict__ wr,
        int2* __restrict__ topk_idx, float2* __restrict__ topk_gate)
{
    const int token = blockIdx.x * 4 + (threadIdx.x >> 6);
    const int lane  = threadIdx.x & 63;
    const float* xr = x + (size_t)token * DMODEL + lane * 16;
    float acc[NEXP];
#pragma unroll
    for (int e = 0; e < NEXP; e++) acc[e] = 0.f;
#pragma unroll
    for (int j = 0; j < 4; j++) {
        float4 xv = ((const float4*)xr)[j];
#pragma unroll
        for (int e = 0; e < NEXP; e++) {
            float4 wv = ((const float4*)(wr + e * DMODEL + lane * 16))[j];
            acc[e] += xv.x * wv.x + xv.y * wv.y + xv.z * wv.z + xv.w * wv.w;
        }
    }
#pragma unroll
    for (int off = 32; off >= 1; off >>= 1) {
#pragma unroll
        for (int e = 0; e < NEXP; e++) acc[e] += __shfl_xor(acc[e], off, 64);
    }
    if (lane == 0) {
        float m = acc[0];
#pragma unroll
        for (int e = 1; e < NEXP; e++) m = fmaxf(m, acc[e]);
        float den = 0.f, g[NEXP];
#pragma unroll
        for (int e = 0; e < NEXP; e++) { g[e] = __expf(acc[e] - m); den += g[e]; }
        float inv = 1.f / den;
#pragma unroll
        for (int e = 0; e < NEXP; e++) g[e] *= inv;
        int i0 = 0; float l0 = acc[0];
#pragma unroll
        for (int e = 1; e < NEXP; e++) if (acc[e] > l0) { l0 = acc[e]; i0 = e; }
        int i1 = -1; float l1 = -1e30f;
#pragma unroll
        for (int e = 0; e < NEXP; e++) if (e != i0 && acc[e] > l1) { l1 = acc[e]; i1 = e; }
        topk_idx[token]  = make_int2(i0, i1);
        topk_gate[token] = make_float2(g[i0], g[i1]);
    }
}

// ---------------- fp32 -> bf16 conversion: two arrays in one dispatch ----------------
__global__ __launch_bounds__(256) void convert2_kernel(
        const float* __restrict__ a, short* __restrict__ da, size_t na,
        const float* __restrict__ b, short* __restrict__ db)
{
    size_t i = ((size_t)blockIdx.x * 256 + threadIdx.x) * 8;
    const float* src; short* dst;
    if (i < na) { src = a + i; dst = da + i; }
    else        { src = b + (i - na); dst = db + (i - na); }
    float4 v0 = ((const float4*)src)[0];
    float4 v1 = ((const float4*)src)[1];
    short8 s = { f2bf(v0.x), f2bf(v0.y), f2bf(v0.z), f2bf(v0.w),
                 f2bf(v1.x), f2bf(v1.y), f2bf(v1.z), f2bf(v1.w) };
    *(short8*)dst = s;
}

// ---------------- Capacity scan + gather/combine metadata (exact cumsum) ------------
__global__ __launch_bounds__(1024) void scan_kernel(
        const int2* __restrict__ topk_idx, const float2* __restrict__ topk_gate,
        int* __restrict__ gtok, float* __restrict__ gw, int* __restrict__ gcnt,
        int2* __restrict__ tslot, float2* __restrict__ tw)
{
    __shared__ unsigned long long wt0[16], wt1[16];
    const int th = threadIdx.x, lane = th & 63, wid = th >> 6;
    int2 idx[4]; float2 gt[4];
#pragma unroll
    for (int j = 0; j < 4; j++) { idx[j] = topk_idx[th * 4 + j]; gt[j] = topk_gate[th * 4 + j]; }
    unsigned long long c0 = 0, c1 = 0;   // experts 0-3 / 4-7, 16-bit fields
#pragma unroll
    for (int j = 0; j < 4; j++) {
        int e0 = idx[j].x, e1 = idx[j].y;
        if (e0 < 4) c0 += 1ull << (e0 * 16); else c1 += 1ull << ((e0 - 4) * 16);
        if (e1 < 4) c0 += 1ull << (e1 * 16); else c1 += 1ull << ((e1 - 4) * 16);
    }
    const unsigned long long my0 = c0, my1 = c1;
#pragma unroll
    for (int d = 1; d < 64; d <<= 1) {
        unsigned long long t0 = __shfl_up(c0, d, 64);
        unsigned long long t1 = __shfl_up(c1, d, 64);
        if (lane >= d) { c0 += t0; c1 += t1; }
    }
    if (lane == 63) { wt0[wid] = c0; wt1[wid] = c1; }
    __syncthreads();
    unsigned long long o0 = 0, o1 = 0;
    for (int w = 0; w < wid; w++) { o0 += wt0[w]; o1 += wt1[w]; }
    c0 += o0; c1 += o1;
    if (th == 1023) {
#pragma unroll
        for (int e = 0; e < 4; e++) gcnt[e]     = min((int)((c0 >> (e * 16)) & 0xFFFF), CAP);
#pragma unroll
        for (int e = 0; e < 4; e++) gcnt[4 + e] = min((int)((c1 >> (e * 16)) & 0xFFFF), CAP);
    }
    const unsigned long long x0 = c0 - my0, x1 = c1 - my1;  // exclusive
    int base[NEXP];
#pragma unroll
    for (int e = 0; e < 4; e++) base[e]     = (int)((x0 >> (e * 16)) & 0xFFFF);
#pragma unroll
    for (int e = 0; e < 4; e++) base[4 + e] = (int)((x1 >> (e * 16)) & 0xFFFF);
#pragma unroll
    for (int j = 0; j < 4; j++) {
        const int n = th * 4 + j;
        const int e0 = idx[j].x, e1 = idx[j].y;
        const int p0 = base[e0]++;
        const int p1 = base[e1]++;
        const bool k0 = p0 < CAP, k1 = p1 < CAP;
        const float gg0 = k0 ? gt[j].x : 0.f, gg1 = k1 ? gt[j].y : 0.f;
        const float invs = 1.f / (gg0 + gg1 + 1e-6f);
        const int s0 = k0 ? e0 * CAP + p0 : 0;
        const int s1 = k1 ? e1 * CAP + p1 : 0;
        if (k0) { gtok[s0] = n; gw[s0] = gg0 * invs; }
        if (k1) { gtok[s1] = n; gw[s1] = gg1 * invs; }
        tslot[n] = make_int2(s0, s1);
        tw[n]    = make_float2(gg0 * invs, gg1 * invs);
    }
}

// ---------------- GEMM1 (128x128, fragment-ordered LDS, K-split): Xb @ WGb^T --------
// KS=1: writes silu() to Hid. KS=2: writes raw bf16 partials to Hp[ks]; silu_merge
// finishes. blockIdx.y = m_tile*KS + ks. Grid 16 x 32*KS -> 1024 blocks at KS=2
// (4 blocks/CU; 32 KB LDS -> 4-5 resident) to escape the m102 small-grid regime.
__global__ __launch_bounds__(256) void gemm1_kernel(
        const short* __restrict__ Xb, const short* __restrict__ WGb,
        short* __restrict__ Hid, short* __restrict__ Hp, int KS)
{
    __shared__ __align__(16) short As[128 * 64];
    __shared__ __align__(16) short Bs[128 * 64];
    const int t = threadIdx.x;
    const int wave = t >> 6, lane = t & 63;
    const int m0 = (blockIdx.y / KS) * 128, n0 = blockIdx.x * 128;
    const int ks = blockIdx.y % KS;
    const int wm = (wave >> 1) * 64, wn = (wave & 1) * 64;
    const int lm = lane & 15, lq = lane >> 4;

    const short *ga[4], *gb[4];
    short *la[4], *lb[4];
#pragma unroll
    for (int j = 0; j < 4; j++) {
        const int b   = wave * 4 + j;
        const int row = (b >> 1) * 16 + lm;
        const int col = (b & 1) * 32 + lq * 8;
        la[j] = &As[b * 512 + lane * 8];
        lb[j] = &Bs[b * 512 + lane * 8];
        ga[j] = Xb  + (size_t)(m0 + row) * DMODEL + col;
        gb[j] = WGb + (size_t)(n0 + row) * DMODEL + col;
    }

    f32x4 acc[4][4];
#pragma unroll
    for (int a = 0; a < 4; a++)
#pragma unroll
        for (int b = 0; b < 4; b++) acc[a][b] = (f32x4)(0.f);

    const int kbeg = ks * (DMODEL / KS), kend = kbeg + DMODEL / KS;
    for (int k0 = kbeg; k0 < kend; k0 += 64) {
#pragma unroll
        for (int j = 0; j < 4; j++) { async16(ga[j] + k0, la[j]); async16(gb[j] + k0, lb[j]); }
        __syncthreads();
#pragma unroll
        for (int kk = 0; kk < 2; kk++) {
            short8 af[4], bf[4];
#pragma unroll
            for (int mi = 0; mi < 4; mi++)
                af[mi] = *(const short8*)&As[((((wm >> 4) + mi) * 2 + kk) * 64 + lane) * 8];
#pragma unroll
            for (int ni = 0; ni < 4; ni++)
                bf[ni] = *(const short8*)&Bs[((((wn >> 4) + ni) * 2 + kk) * 64 + lane) * 8];
#pragma unroll
            for (int mi = 0; mi < 4; mi++)
#pragma unroll
                for (int ni = 0; ni < 4; ni++)
                    acc[mi][ni] = __builtin_amdgcn_mfma_f32_16x16x32_bf16(af[mi], bf[ni], acc[mi][ni], 0, 0, 0);
        }
        __syncthreads();
    }
    if (KS == 1) {
#pragma unroll
        for (int mi = 0; mi < 4; mi++)
#pragma unroll
            for (int i = 0; i < 4; i++) {
                const int row = m0 + wm + mi * 16 + lq * 4 + i;
#pragma unroll
                for (int ni = 0; ni < 4; ni++) {
                    const int col = n0 + wn + ni * 16 + lm;
                    const float v = acc[mi][ni][i];
                    Hid[(size_t)row * DHID + col] = f2bf(v / (1.f + __expf(-v)));
                }
            }
    } else {
        short* Ho = Hp + (size_t)ks * NTOK * DHID;
#pragma unroll
        for (int mi = 0; mi < 4; mi++)
#pragma unroll
            for (int i = 0; i < 4; i++) {
                const int row = m0 + wm + mi * 16 + lq * 4 + i;
#pragma unroll
                for (int ni = 0; ni < 4; ni++) {
                    const int col = n0 + wn + ni * 16 + lm;
                    Ho[(size_t)row * DHID + col] = f2bf(acc[mi][ni][i]);
                }
            }
    }
}

// ---------------- silu_merge: Hid = silu(Hp[0] + Hp[1]) ----------------
__global__ __launch_bounds__(256) void silu_merge_kernel(
        const short* __restrict__ Hp, short* __restrict__ Hid)
{
    const size_t i = ((size_t)blockIdx.x * 256 + threadIdx.x) * 8;
    const unsigned short* p0 = (const unsigned short*)Hp + i;
    const unsigned short* p1 = (const unsigned short*)Hp + (size_t)NTOK * DHID + i;
    ushort4 a0 = *(const ushort4*)p0, a1 = *(const ushort4*)(p0 + 4);
    ushort4 b0 = *(const ushort4*)p1, b1 = *(const ushort4*)(p1 + 4);
    float v[8] = { bf2f(a0.x) + bf2f(b0.x), bf2f(a0.y) + bf2f(b0.y),
                   bf2f(a0.z) + bf2f(b0.z), bf2f(a0.w) + bf2f(b0.w),
                   bf2f(a1.x) + bf2f(b1.x), bf2f(a1.y) + bf2f(b1.y),
                   bf2f(a1.z) + bf2f(b1.z), bf2f(a1.w) + bf2f(b1.w) };
    short8 o;
#pragma unroll
    for (int j = 0; j < 8; j++) o[j] = f2bf(v[j] / (1.f + __expf(-v[j])));
    *(short8*)(Hid + i) = o;
}

// ---------------- GEMM2 (128x128, fragment-ordered, K-split, no atomics) ------------
// Yp[ks][slot] = A@B^T over K-chunk ks. blockIdx.z = m_tile*KS + ks.
// Grid 8 x 8 x 5*KS -> 1280 blocks at KS=4 (5/CU; 33 KB LDS -> 4 resident).
__global__ __launch_bounds__(256) void gemm2_kernel(
        const short* __restrict__ Hid, const short* __restrict__ WDb,
        const int* __restrict__ gtok, const int* __restrict__ gcnt,
        short* __restrict__ Yp, int KS)
{
    __shared__ __align__(16) short As[128 * 64];
    __shared__ __align__(16) short Bs[128 * 64];
    __shared__ int tok_s[128];
    const int e  = blockIdx.x;             // gridDim.x=8 -> linear%8==e -> XCD pinning
    const int n0 = blockIdx.y * 128;
    const int m0 = (blockIdx.z / KS) * 128;
    const int ks = blockIdx.z % KS;
    const int cnt = gcnt[e];
    if (m0 >= cnt) return;
    const int t = threadIdx.x;
    const int wave = t >> 6, lane = t & 63;
    const int wm = (wave >> 1) * 64, wn = (wave & 1) * 64;
    const int lm = lane & 15, lq = lane >> 4;
    const short* WDe = WDb + (size_t)e * DMODEL * DHID;

    if (t < 128) tok_s[t] = (m0 + t < cnt) ? gtok[e * CAP + m0 + t] : 0;
    __syncthreads();

    const short *ga[4], *gb[4];
    short *la[4], *lb[4];
#pragma unroll
    for (int j = 0; j < 4; j++) {
        const int b   = wave * 4 + j;
        const int row = (b >> 1) * 16 + lm;
        const int col = (b & 1) * 32 + lq * 8;
        la[j] = &As[b * 512 + lane * 8];
        lb[j] = &Bs[b * 512 + lane * 8];
        ga[j] = Hid + (size_t)tok_s[row] * DHID + col;
        gb[j] = WDe + (size_t)(n0 + row) * DHID + col;
    }

    f32x4 acc[4][4];
#pragma unroll
    for (int a = 0; a < 4; a++)
#pragma unroll
        for (int b = 0; b < 4; b++) acc[a][b] = (f32x4)(0.f);

    const int kbeg = ks * (DHID / KS), kend = kbeg + DHID / KS;
    for (int k0 = kbeg; k0 < kend; k0 += 64) {
#pragma unroll
        for (int j = 0; j < 4; j++) { async16(ga[j] + k0, la[j]); async16(gb[j] + k0, lb[j]); }
        __syncthreads();
#pragma unroll
        for (int kk = 0; kk < 2; kk++) {
            short8 af[4], bf[4];
#pragma unroll
            for (int mi = 0; mi < 4; mi++)
                af[mi] = *(const short8*)&As[((((wm >> 4) + mi) * 2 + kk) * 64 + lane) * 8];
#pragma unroll
            for (int ni = 0; ni < 4; ni++)
                bf[ni] = *(const short8*)&Bs[((((wn >> 4) + ni) * 2 + kk) * 64 + lane) * 8];
#pragma unroll
            for (int mi = 0; mi < 4; mi++)
#pragma unroll
                for (int ni = 0; ni < 4; ni++)
                    acc[mi][ni] = __builtin_amdgcn_mfma_f32_16x16x32_bf16(af[mi], bf[ni], acc[mi][ni], 0, 0, 0);
        }
        __syncthreads();
    }
    short* Yo = Yp + (size_t)ks * SLOTS * DMODEL;
#pragma unroll
    for (int mi = 0; mi < 4; mi++)
#pragma unroll
        for (int i = 0; i < 4; i++) {
            const int slot = e * CAP + m0 + wm + mi * 16 + lq * 4 + i;
#pragma unroll
            for (int ni = 0; ni < 4; ni++) {
                const int col = n0 + wn + ni * 16 + lm;
                Yo[(size_t)slot * DMODEL + col] = f2bf(acc[mi][ni][i]);
            }
        }
}

// ---------------- Combine: y[n] = w0*sum_ks Yp[ks][s0] + w1*sum_ks Yp[ks][s1] -------
__global__ __launch_bounds__(256) void combine_kernel(
        const short* __restrict__ Yp, const int2* __restrict__ tslot,
        const float2* __restrict__ tw, float* __restrict__ y, int KS)
{
    const int token = blockIdx.x;
    const int c = threadIdx.x * 4;
    const int2   s = tslot[token];
    const float2 w = tw[token];
    float4 o = make_float4(0.f, 0.f, 0.f, 0.f);
    for (int ks = 0; ks < KS; ks++) {
        const unsigned short* base = (const unsigned short*)Yp + (size_t)ks * SLOTS * DMODEL;
        ushort4 a = *(const ushort4*)(base + (size_t)s.x * DMODEL + c);
        ushort4 b = *(const ushort4*)(base + (size_t)s.y * DMODEL + c);
        o.x += w.x * bf2f(a.x) + w.y * bf2f(b.x);
        o.y += w.x * bf2f(a.y) + w.y * bf2f(b.y);
        o.z += w.x * bf2f(a.z) + w.y * bf2f(b.z);
        o.w += w.x * bf2f(a.w) + w.y * bf2f(b.w);
    }
    *(float4*)&y[(size_t)token * DMODEL + c] = o;
}

// ---------------- Fallback GEMMs (round-0 proven, fp32 inline-convert) ----------------
__global__ __launch_bounds__(256) void gemm1_fb_kernel(
        const float* __restrict__ X, const float* __restrict__ WG, short* __restrict__ Hid)
{
    __shared__ short As[128][72];
    __shared__ short Bs[128][72];
    const int t = threadIdx.x;
    const int wave = t >> 6, lane = t & 63;
    const int m0 = blockIdx.y * 128, n0 = blockIdx.x * 128;
    const int wm = (wave >> 1) * 64, wn = (wave & 1) * 64;
    const int lm = lane & 15, lq = lane >> 4, lk = lq * 8;
    const int r0 = t >> 3, c8 = (t & 7) * 8;

    f32x4 acc[4][4];
#pragma unroll
    for (int a = 0; a < 4; a++)
#pragma unroll
        for (int b = 0; b < 4; b++) acc[a][b] = (f32x4)(0.f);

    for (int k0 = 0; k0 < DMODEL; k0 += 64) {
#pragma unroll
        for (int i = 0; i < 4; i++) {
            const int row = r0 + i * 32;
            const float* ga = X + (size_t)(m0 + row) * DMODEL + k0 + c8;
            float4 v0 = ((const float4*)ga)[0];
            float4 v1 = ((const float4*)ga)[1];
            short8 s = { f2bf(v0.x), f2bf(v0.y), f2bf(v0.z), f2bf(v0.w),
                         f2bf(v1.x), f2bf(v1.y), f2bf(v1.z), f2bf(v1.w) };
            *(short8*)&As[row][c8] = s;
            const float* gb = WG + (size_t)(n0 + row) * DMODEL + k0 + c8;
            float4 w0 = ((const float4*)gb)[0];
            float4 w1 = ((const float4*)gb)[1];
            short8 sw = { f2bf(w0.x), f2bf(w0.y), f2bf(w0.z), f2bf(w0.w),
                          f2bf(w1.x), f2bf(w1.y), f2bf(w1.z), f2bf(w1.w) };
            *(short8*)&Bs[row][c8] = sw;
        }
        __syncthreads();
#pragma unroll
        for (int kk = 0; kk < 64; kk += 32) {
            short8 af[4], bf[4];
#pragma unroll
            for (int mi = 0; mi < 4; mi++) af[mi] = *(const short8*)&As[wm + mi * 16 + lm][kk + lk];
#pragma unroll
            for (int ni = 0; ni < 4; ni++) bf[ni] = *(const short8*)&Bs[wn + ni * 16 + lm][kk + lk];
#pragma unroll
            for (int mi = 0; mi < 4; mi++)
#pragma unroll
                for (int ni = 0; ni < 4; ni++)
                    acc[mi][ni] = __builtin_amdgcn_mfma_f32_16x16x32_bf16(af[mi], bf[ni], acc[mi][ni], 0, 0, 0);
        }
        __syncthreads();
    }
#pragma unroll
    for (int mi = 0; mi < 4; mi++)
#pragma unroll
        for (int i = 0; i < 4; i++) {
            const int row = m0 + wm + mi * 16 + lq * 4 + i;
#pragma unroll
            for (int ni = 0; ni < 4; ni++) {
                const int col = n0 + wn + ni * 16 + lm;
                const float v = acc[mi][ni][i];
                const float s = v / (1.f + __expf(-v));
                Hid[(size_t)row * DHID + col] = f2bf(s);
            }
        }
}

__global__ __launch_bounds__(256) void gemm2_fb_kernel(
        const short* __restrict__ Hid, const float* __restrict__ WD,
        const int* __restrict__ gtok, const float* __restrict__ gw,
        const int* __restrict__ gcnt, float* __restrict__ Y)
{
    __shared__ short As[128][72];
    __shared__ short Bs[128][72];
    __shared__ int   tok_s[128];
    __shared__ float w_s[128];
    const int e = blockIdx.z;
    const int cnt = gcnt[e];
    const int m0 = blockIdx.y * 128;
    if (m0 >= cnt) return;
    const int n0 = blockIdx.x * 128;
    const int t = threadIdx.x;
    const int wave = t >> 6, lane = t & 63;
    const int wm = (wave >> 1) * 64, wn = (wave & 1) * 64;
    const int lm = lane & 15, lq = lane >> 4, lk = lq * 8;
    const int r0 = t >> 3, c8 = (t & 7) * 8;
    const float* WDe = WD + (size_t)e * DMODEL * DHID;

    if (t < 128) {
        const int r = m0 + t;
        const bool v = r < cnt;
        tok_s[t] = v ? gtok[e * CAP + r] : 0;
        w_s[t]   = v ? gw[e * CAP + r] : 0.f;
    }
    __syncthreads();

    f32x4 acc[4][4];
#pragma unroll
    for (int a = 0; a < 4; a++)
#pragma unroll
        for (int b = 0; b < 4; b++) acc[a][b] = (f32x4)(0.f);

    const int tokA[4] = { tok_s[r0], tok_s[r0 + 32], tok_s[r0 + 64], tok_s[r0 + 96] };

    for (int k0 = 0; k0 < DHID; k0 += 64) {
#pragma unroll
        for (int i = 0; i < 4; i++) {
            const int row = r0 + i * 32;
            uint4 av = *(const uint4*)(Hid + (size_t)tokA[i] * DHID + k0 + c8);
            *(uint4*)&As[row][c8] = av;
            const float* gb = WDe + (size_t)(n0 + row) * DHID + k0 + c8;
            float4 w0 = ((const float4*)gb)[0];
            float4 w1 = ((const float4*)gb)[1];
            short8 sw = { f2bf(w0.x), f2bf(w0.y), f2bf(w0.z), f2bf(w0.w),
                          f2bf(w1.x), f2bf(w1.y), f2bf(w1.z), f2bf(w1.w) };
            *(short8*)&Bs[row][c8] = sw;
        }
        __syncthreads();
#pragma unroll
        for (int kk = 0; kk < 64; kk += 32) {
            short8 af[4], bf[4];
#pragma unroll
            for (int mi = 0; mi < 4; mi++) af[mi] = *(const short8*)&As[wm + mi * 16 + lm][kk + lk];
#pragma unroll
            for (int ni = 0; ni < 4; ni++) bf[ni] = *(const short8*)&Bs[wn + ni * 16 + lm][kk + lk];
#pragma unroll
            for (int mi = 0; mi < 4; mi++)
#pragma unroll
                for (int ni = 0; ni < 4; ni++)
                    acc[mi][ni] = __builtin_amdgcn_mfma_f32_16x16x32_bf16(af[mi], bf[ni], acc[mi][ni], 0, 0, 0);
        }
        __syncthreads();
    }
#pragma unroll
    for (int mi = 0; mi < 4; mi++)
#pragma unroll
        for (int i = 0; i < 4; i++) {
            const int r = wm + mi * 16 + lq * 4 + i;
            const float wr = w_s[r];
            if (wr > 0.f) {
                const int token = tok_s[r];
#pragma unroll
                for (int ni = 0; ni < 4; ni++) {
                    const int col = n0 + wn + ni * 16 + lm;
                    atomicAdd(&Y[(size_t)token * DMODEL + col], acc[mi][ni][i] * wr);
                }
            }
        }
}

extern "C" void kernel_launch(void* const* d_in, const int* in_sizes, int n_in,
                              void* d_out, int out_size, void* d_ws, size_t ws_size,
                              hipStream_t stream) {
    const float* x  = (const float*)d_in[0];
    const float* wr = (const float*)d_in[1];
    const float* wg = (const float*)d_in[2];
    const float* wd = (const float*)d_in[3];
    float* y = (float*)d_out;

    char* w = (char*)d_ws;
    int2*   topk_idx  = (int2*)w;    w += NTOK * sizeof(int2);
    float2* topk_gate = (float2*)w;  w += NTOK * sizeof(float2);
    int*    gtok      = (int*)w;     w += NEXP * CAP * sizeof(int);
    float*  gw        = (float*)w;   w += NEXP * CAP * sizeof(float);
    int*    gcnt      = (int*)w;     w += 256;
    int2*   tslot     = (int2*)w;    w += NTOK * sizeof(int2);
    float2* tw        = (float2*)w;  w += NTOK * sizeof(float2);
    short*  Hid       = (short*)w;   w += (size_t)NTOK * DHID * sizeof(short);
    short*  WDb       = (short*)w;   w += (size_t)NEXP * DMODEL * DHID * sizeof(short);
    // Xb (8 MB) + WGb (4 MB) die after gemm1; Hp (33.5 MB) dies after silu_merge.
    // Yp (KS2 * 5120 * 1024 bf16) aliases the contiguous Xb..Hp span.
    short*  Xb        = (short*)w;
    short*  WGb       = (short*)(w + (size_t)NTOK * DMODEL * sizeof(short));
    short*  Yp        = (short*)w;
    char*   w63       = w + ((size_t)NTOK * DMODEL + (size_t)DHID * DMODEL) * sizeof(short);
    short*  Hp        = (short*)w63;
    char*   w96       = w63 + (size_t)2 * NTOK * DHID * sizeof(short);
    const size_t need63 = (size_t)(w63 - (char*)d_ws);   // KS=1 everywhere
    const size_t need96 = (size_t)(w96 - (char*)d_ws);   // gemm1 KS=2, gemm2 KS=4

    if (ws_size >= need63) {
        const int KS1 = (ws_size >= need96) ? 2 : 1;
        const int KS2 = (ws_size >= need96) ? 4 : 1;
        router_kernel<<<NTOK / 4, 256, 0, stream>>>(x, wr, Xb, topk_idx, topk_gate);
        convert2_kernel<<<(DHID * DMODEL + NEXP * DMODEL * DHID) / (256 * 8), 256, 0, stream>>>(
            wg, WGb, (size_t)DHID * DMODEL, wd, WDb);
        scan_kernel<<<1, 1024, 0, stream>>>(topk_idx, topk_gate, gtok, gw, gcnt, tslot, tw);
        gemm1_kernel<<<dim3(DHID / 128, (NTOK / 128) * KS1), 256, 0, stream>>>(
            Xb, WGb, Hid, Hp, KS1);
        if (KS1 == 2)
            silu_merge_kernel<<<(NTOK * DHID) / (256 * 8), 256, 0, stream>>>(Hp, Hid);
        gemm2_kernel<<<dim3(NEXP, DMODEL / 128, (CAP / 128) * KS2), 256, 0, stream>>>(
            Hid, WDb, gtok, gcnt, Yp, KS2);
        combine_kernel<<<NTOK, 256, 0, stream>>>(Yp, tslot, tw, y, KS2);
    } else {
        hipMemsetAsync(y, 0, (size_t)NTOK * DMODEL * sizeof(float), stream);
        router_fb_kernel<<<NTOK / 4, 256, 0, stream>>>(x, wr, topk_idx, topk_gate);
        scan_kernel<<<1, 1024, 0, stream>>>(topk_idx, topk_gate, gtok, gw, gcnt, tslot, tw);
        gemm1_fb_kernel<<<dim3(DHID / 128, NTOK / 128), 256, 0, stream>>>(x, wg, Hid);
        gemm2_fb_kernel<<<dim3(DMODEL / 128, (CAP + 127) / 128, NEXP), 256, 0, stream>>>(
            Hid, wd, gtok, gw, gcnt, y);
    }
}

// Round 8
// 238.487 us; speedup vs baseline: 1.1196x; 1.0444x over previous
//
#include <hip/hip_runtime.h>
#include <hip/hip_bf16.h>
#include <math.h>

#define NTOK 4096
#define DMODEL 1024
#define DHID 2048
#define NEXP 8
#define CAP 640
#define SLOTS (NEXP * CAP)
#define NWG ((size_t)DHID * DMODEL)
#define NWD ((size_t)NEXP * DMODEL * DHID)

typedef __attribute__((ext_vector_type(8))) short short8;
typedef __attribute__((ext_vector_type(4))) float f32x4;

__device__ inline short f2bf(float f) {
    union { float f; unsigned u; } v; v.f = f;
    unsigned r = v.u + 0x7FFF + ((v.u >> 16) & 1);   // RNE (inputs are finite)
    return (short)(r >> 16);
}
__device__ inline float bf2f(unsigned short u) {
    union { unsigned u; float f; } v; v.u = ((unsigned)u) << 16; return v.f;
}
__device__ inline void async16(const short* g, short* l) {
    __builtin_amdgcn_global_load_lds(
        (const __attribute__((address_space(1))) unsigned*)g,
        (__attribute__((address_space(3))) unsigned*)l, 16, 0, 0);
}

// ---------------- prep: weight fp32->bf16 convert (all blocks) + router (blocks<1024)
// Grid 9216 x 256: 9216*2048 == NWG+NWD exactly. Fuses 3 old launches into 1.
__global__ __launch_bounds__(256) void prep_kernel(
        const float* __restrict__ x, const float* __restrict__ wr, short* __restrict__ Xb,
        int2* __restrict__ topk_idx, float2* __restrict__ topk_gate,
        const float* __restrict__ wg, short* __restrict__ WGb,
        const float* __restrict__ wd, short* __restrict__ WDb)
{
    // ---- convert slice (every block) ----
    {
        const size_t ci = ((size_t)blockIdx.x * 256 + threadIdx.x) * 8;
        const float* src; short* dst;
        if (ci < NWG) { src = wg + ci; dst = WGb + ci; }
        else          { src = wd + (ci - NWG); dst = WDb + (ci - NWG); }
        float4 v0 = ((const float4*)src)[0];
        float4 v1 = ((const float4*)src)[1];
        short8 s = { f2bf(v0.x), f2bf(v0.y), f2bf(v0.z), f2bf(v0.w),
                     f2bf(v1.x), f2bf(v1.y), f2bf(v1.z), f2bf(v1.w) };
        *(short8*)dst = s;
    }
    // ---- router (first 1024 blocks, 4 tokens each, 1 wave/token) ----
    if (blockIdx.x >= NTOK / 4) return;
    const int token = blockIdx.x * 4 + (threadIdx.x >> 6);
    const int lane  = threadIdx.x & 63;
    const float* xr = x + (size_t)token * DMODEL + lane * 16;
    float4 xv[4];
#pragma unroll
    for (int j = 0; j < 4; j++) xv[j] = ((const float4*)xr)[j];
    short8 s0 = { f2bf(xv[0].x), f2bf(xv[0].y), f2bf(xv[0].z), f2bf(xv[0].w),
                  f2bf(xv[1].x), f2bf(xv[1].y), f2bf(xv[1].z), f2bf(xv[1].w) };
    short8 s1 = { f2bf(xv[2].x), f2bf(xv[2].y), f2bf(xv[2].z), f2bf(xv[2].w),
                  f2bf(xv[3].x), f2bf(xv[3].y), f2bf(xv[3].z), f2bf(xv[3].w) };
    short* xo = Xb + (size_t)token * DMODEL + lane * 16;
    *(short8*)xo = s0;
    *(short8*)(xo + 8) = s1;

    float acc[NEXP];
#pragma unroll
    for (int e = 0; e < NEXP; e++) acc[e] = 0.f;
#pragma unroll
    for (int j = 0; j < 4; j++) {
#pragma unroll
        for (int e = 0; e < NEXP; e++) {
            float4 wv = ((const float4*)(wr + e * DMODEL + lane * 16))[j];
            acc[e] += xv[j].x * wv.x + xv[j].y * wv.y + xv[j].z * wv.z + xv[j].w * wv.w;
        }
    }
#pragma unroll
    for (int off = 32; off >= 1; off >>= 1) {
#pragma unroll
        for (int e = 0; e < NEXP; e++) acc[e] += __shfl_xor(acc[e], off, 64);
    }
    if (lane == 0) {
        float m = acc[0];
#pragma unroll
        for (int e = 1; e < NEXP; e++) m = fmaxf(m, acc[e]);
        float den = 0.f, g[NEXP];
#pragma unroll
        for (int e = 0; e < NEXP; e++) { g[e] = __expf(acc[e] - m); den += g[e]; }
        float inv = 1.f / den;
#pragma unroll
        for (int e = 0; e < NEXP; e++) g[e] *= inv;
        int i0 = 0; float l0 = acc[0];
#pragma unroll
        for (int e = 1; e < NEXP; e++) if (acc[e] > l0) { l0 = acc[e]; i0 = e; }
        int i1 = -1; float l1 = -1e30f;
#pragma unroll
        for (int e = 0; e < NEXP; e++) if (e != i0 && acc[e] > l1) { l1 = acc[e]; i1 = e; }
        topk_idx[token]  = make_int2(i0, i1);
        topk_gate[token] = make_float2(g[i0], g[i1]);
    }
}

// legacy router (fallback path, no Xb)
__global__ __launch_bounds__(256) void router_fb_kernel(
        const float* __restrict__ x, const float* __restrict__ wr,
        int2* __restrict__ topk_idx, float2* __restrict__ topk_gate)
{
    const int token = blockIdx.x * 4 + (threadIdx.x >> 6);
    const int lane  = threadIdx.x & 63;
    const float* xr = x + (size_t)token * DMODEL + lane * 16;
    float acc[NEXP];
#pragma unroll
    for (int e = 0; e < NEXP; e++) acc[e] = 0.f;
#pragma unroll
    for (int j = 0; j < 4; j++) {
        float4 xv = ((const float4*)xr)[j];
#pragma unroll
        for (int e = 0; e < NEXP; e++) {
            float4 wv = ((const float4*)(wr + e * DMODEL + lane * 16))[j];
            acc[e] += xv.x * wv.x + xv.y * wv.y + xv.z * wv.z + xv.w * wv.w;
        }
    }
#pragma unroll
    for (int off = 32; off >= 1; off >>= 1) {
#pragma unroll
        for (int e = 0; e < NEXP; e++) acc[e] += __shfl_xor(acc[e], off, 64);
    }
    if (lane == 0) {
        float m = acc[0];
#pragma unroll
        for (int e = 1; e < NEXP; e++) m = fmaxf(m, acc[e]);
        float den = 0.f, g[NEXP];
#pragma unroll
        for (int e = 0; e < NEXP; e++) { g[e] = __expf(acc[e] - m); den += g[e]; }
        float inv = 1.f / den;
#pragma unroll
        for (int e = 0; e < NEXP; e++) g[e] *= inv;
        int i0 = 0; float l0 = acc[0];
#pragma unroll
        for (int e = 1; e < NEXP; e++) if (acc[e] > l0) { l0 = acc[e]; i0 = e; }
        int i1 = -1; float l1 = -1e30f;
#pragma unroll
        for (int e = 0; e < NEXP; e++) if (e != i0 && acc[e] > l1) { l1 = acc[e]; i1 = e; }
        topk_idx[token]  = make_int2(i0, i1);
        topk_gate[token] = make_float2(g[i0], g[i1]);
    }
}

// ---------------- Capacity scan + gather/combine metadata (exact cumsum) ------------
__global__ __launch_bounds__(1024) void scan_kernel(
        const int2* __restrict__ topk_idx, const float2* __restrict__ topk_gate,
        int* __restrict__ gtok, float* __restrict__ gw, int* __restrict__ gcnt,
        int2* __restrict__ tslot, float2* __restrict__ tw)
{
    __shared__ unsigned long long wt0[16], wt1[16];
    const int th = threadIdx.x, lane = th & 63, wid = th >> 6;
    int2 idx[4]; float2 gt[4];
#pragma unroll
    for (int j = 0; j < 4; j++) { idx[j] = topk_idx[th * 4 + j]; gt[j] = topk_gate[th * 4 + j]; }
    unsigned long long c0 = 0, c1 = 0;   // experts 0-3 / 4-7, 16-bit fields
#pragma unroll
    for (int j = 0; j < 4; j++) {
        int e0 = idx[j].x, e1 = idx[j].y;
        if (e0 < 4) c0 += 1ull << (e0 * 16); else c1 += 1ull << ((e0 - 4) * 16);
        if (e1 < 4) c0 += 1ull << (e1 * 16); else c1 += 1ull << ((e1 - 4) * 16);
    }
    const unsigned long long my0 = c0, my1 = c1;
#pragma unroll
    for (int d = 1; d < 64; d <<= 1) {
        unsigned long long t0 = __shfl_up(c0, d, 64);
        unsigned long long t1 = __shfl_up(c1, d, 64);
        if (lane >= d) { c0 += t0; c1 += t1; }
    }
    if (lane == 63) { wt0[wid] = c0; wt1[wid] = c1; }
    __syncthreads();
    unsigned long long o0 = 0, o1 = 0;
    for (int w = 0; w < wid; w++) { o0 += wt0[w]; o1 += wt1[w]; }
    c0 += o0; c1 += o1;
    if (th == 1023) {
#pragma unroll
        for (int e = 0; e < 4; e++) gcnt[e]     = min((int)((c0 >> (e * 16)) & 0xFFFF), CAP);
#pragma unroll
        for (int e = 0; e < 4; e++) gcnt[4 + e] = min((int)((c1 >> (e * 16)) & 0xFFFF), CAP);
    }
    const unsigned long long x0 = c0 - my0, x1 = c1 - my1;  // exclusive
    int base[NEXP];
#pragma unroll
    for (int e = 0; e < 4; e++) base[e]     = (int)((x0 >> (e * 16)) & 0xFFFF);
#pragma unroll
    for (int e = 0; e < 4; e++) base[4 + e] = (int)((x1 >> (e * 16)) & 0xFFFF);
#pragma unroll
    for (int j = 0; j < 4; j++) {
        const int n = th * 4 + j;
        const int e0 = idx[j].x, e1 = idx[j].y;
        const int p0 = base[e0]++;
        const int p1 = base[e1]++;
        const bool k0 = p0 < CAP, k1 = p1 < CAP;
        const float gg0 = k0 ? gt[j].x : 0.f, gg1 = k1 ? gt[j].y : 0.f;
        const float invs = 1.f / (gg0 + gg1 + 1e-6f);
        const int s0 = k0 ? e0 * CAP + p0 : 0;
        const int s1 = k1 ? e1 * CAP + p1 : 0;
        if (k0) { gtok[s0] = n; gw[s0] = gg0 * invs; }
        if (k1) { gtok[s1] = n; gw[s1] = gg1 * invs; }
        tslot[n] = make_int2(s0, s1);
        tw[n]    = make_float2(gg0 * invs, gg1 * invs);
    }
}

// ---------------- GEMM1 (128x128, fragment-ordered LDS): hidden = silu(Xb@WGb^T) ----
__global__ __launch_bounds__(256) void gemm1_kernel(
        const short* __restrict__ Xb, const short* __restrict__ WGb, short* __restrict__ Hid)
{
    __shared__ __align__(16) short As[128 * 64];
    __shared__ __align__(16) short Bs[128 * 64];
    const int t = threadIdx.x;
    const int wave = t >> 6, lane = t & 63;
    const int m0 = blockIdx.y * 128, n0 = blockIdx.x * 128;
    const int wm = (wave >> 1) * 64, wn = (wave & 1) * 64;
    const int lm = lane & 15, lq = lane >> 4;

    const short *ga[4], *gb[4];
    short *la[4], *lb[4];
#pragma unroll
    for (int j = 0; j < 4; j++) {
        const int b   = wave * 4 + j;
        const int row = (b >> 1) * 16 + lm;
        const int col = (b & 1) * 32 + lq * 8;
        la[j] = &As[b * 512 + lane * 8];
        lb[j] = &Bs[b * 512 + lane * 8];
        ga[j] = Xb  + (size_t)(m0 + row) * DMODEL + col;
        gb[j] = WGb + (size_t)(n0 + row) * DMODEL + col;
    }

    f32x4 acc[4][4];
#pragma unroll
    for (int a = 0; a < 4; a++)
#pragma unroll
        for (int b = 0; b < 4; b++) acc[a][b] = (f32x4)(0.f);

    for (int k0 = 0; k0 < DMODEL; k0 += 64) {
#pragma unroll
        for (int j = 0; j < 4; j++) { async16(ga[j] + k0, la[j]); async16(gb[j] + k0, lb[j]); }
        __syncthreads();
#pragma unroll
        for (int kk = 0; kk < 2; kk++) {
            short8 af[4], bf[4];
#pragma unroll
            for (int mi = 0; mi < 4; mi++)
                af[mi] = *(const short8*)&As[((((wm >> 4) + mi) * 2 + kk) * 64 + lane) * 8];
#pragma unroll
            for (int ni = 0; ni < 4; ni++)
                bf[ni] = *(const short8*)&Bs[((((wn >> 4) + ni) * 2 + kk) * 64 + lane) * 8];
#pragma unroll
            for (int mi = 0; mi < 4; mi++)
#pragma unroll
                for (int ni = 0; ni < 4; ni++)
                    acc[mi][ni] = __builtin_amdgcn_mfma_f32_16x16x32_bf16(af[mi], bf[ni], acc[mi][ni], 0, 0, 0);
        }
        __syncthreads();
    }
#pragma unroll
    for (int mi = 0; mi < 4; mi++)
#pragma unroll
        for (int i = 0; i < 4; i++) {
            const int row = m0 + wm + mi * 16 + lq * 4 + i;
#pragma unroll
            for (int ni = 0; ni < 4; ni++) {
                const int col = n0 + wn + ni * 16 + lm;
                const float v = acc[mi][ni][i];
                Hid[(size_t)row * DHID + col] = f2bf(v / (1.f + __expf(-v)));
            }
        }
}

// ---------------- GEMM2 (128x128, fragment-ordered, K-split, no atomics) ------------
// Yp[ks][slot] = A@B^T over K-chunk ks. Grid 8 x 8 x 5*KS -> 1280 blocks at KS=4.
__global__ __launch_bounds__(256) void gemm2_kernel(
        const short* __restrict__ Hid, const short* __restrict__ WDb,
        const int* __restrict__ gtok, const int* __restrict__ gcnt,
        short* __restrict__ Yp, int KS)
{
    __shared__ __align__(16) short As[128 * 64];
    __shared__ __align__(16) short Bs[128 * 64];
    __shared__ int tok_s[128];
    const int e  = blockIdx.x;             // gridDim.x=8 -> linear%8==e -> XCD pinning
    const int n0 = blockIdx.y * 128;
    const int m0 = (blockIdx.z / KS) * 128;
    const int ks = blockIdx.z % KS;
    const int cnt = gcnt[e];
    if (m0 >= cnt) return;
    const int t = threadIdx.x;
    const int wave = t >> 6, lane = t & 63;
    const int wm = (wave >> 1) * 64, wn = (wave & 1) * 64;
    const int lm = lane & 15, lq = lane >> 4;
    const short* WDe = WDb + (size_t)e * DMODEL * DHID;

    if (t < 128) tok_s[t] = (m0 + t < cnt) ? gtok[e * CAP + m0 + t] : 0;
    __syncthreads();

    const short *ga[4], *gb[4];
    short *la[4], *lb[4];
#pragma unroll
    for (int j = 0; j < 4; j++) {
        const int b   = wave * 4 + j;
        const int row = (b >> 1) * 16 + lm;
        const int col = (b & 1) * 32 + lq * 8;
        la[j] = &As[b * 512 + lane * 8];
        lb[j] = &Bs[b * 512 + lane * 8];
        ga[j] = Hid + (size_t)tok_s[row] * DHID + col;
        gb[j] = WDe + (size_t)(n0 + row) * DHID + col;
    }

    f32x4 acc[4][4];
#pragma unroll
    for (int a = 0; a < 4; a++)
#pragma unroll
        for (int b = 0; b < 4; b++) acc[a][b] = (f32x4)(0.f);

    const int kbeg = ks * (DHID / KS), kend = kbeg + DHID / KS;
    for (int k0 = kbeg; k0 < kend; k0 += 64) {
#pragma unroll
        for (int j = 0; j < 4; j++) { async16(ga[j] + k0, la[j]); async16(gb[j] + k0, lb[j]); }
        __syncthreads();
#pragma unroll
        for (int kk = 0; kk < 2; kk++) {
            short8 af[4], bf[4];
#pragma unroll
            for (int mi = 0; mi < 4; mi++)
                af[mi] = *(const short8*)&As[((((wm >> 4) + mi) * 2 + kk) * 64 + lane) * 8];
#pragma unroll
            for (int ni = 0; ni < 4; ni++)
                bf[ni] = *(const short8*)&Bs[((((wn >> 4) + ni) * 2 + kk) * 64 + lane) * 8];
#pragma unroll
            for (int mi = 0; mi < 4; mi++)
#pragma unroll
                for (int ni = 0; ni < 4; ni++)
                    acc[mi][ni] = __builtin_amdgcn_mfma_f32_16x16x32_bf16(af[mi], bf[ni], acc[mi][ni], 0, 0, 0);
        }
        __syncthreads();
    }
    short* Yo = Yp + (size_t)ks * SLOTS * DMODEL;
#pragma unroll
    for (int mi = 0; mi < 4; mi++)
#pragma unroll
        for (int i = 0; i < 4; i++) {
            const int slot = e * CAP + m0 + wm + mi * 16 + lq * 4 + i;
#pragma unroll
            for (int ni = 0; ni < 4; ni++) {
                const int col = n0 + wn + ni * 16 + lm;
                Yo[(size_t)slot * DMODEL + col] = f2bf(acc[mi][ni][i]);
            }
        }
}

// ---------------- Combine: y[n] = w0*sum_ks Yp[ks][s0] + w1*sum_ks Yp[ks][s1] -------
__global__ __launch_bounds__(256) void combine_kernel(
        const short* __restrict__ Yp, const int2* __restrict__ tslot,
        const float2* __restrict__ tw, float* __restrict__ y, int KS)
{
    const int token = blockIdx.x;
    const int c = threadIdx.x * 4;
    const int2   s = tslot[token];
    const float2 w = tw[token];
    float4 o = make_float4(0.f, 0.f, 0.f, 0.f);
    for (int ks = 0; ks < KS; ks++) {
        const unsigned short* base = (const unsigned short*)Yp + (size_t)ks * SLOTS * DMODEL;
        ushort4 a = *(const ushort4*)(base + (size_t)s.x * DMODEL + c);
        ushort4 b = *(const ushort4*)(base + (size_t)s.y * DMODEL + c);
        o.x += w.x * bf2f(a.x) + w.y * bf2f(b.x);
        o.y += w.x * bf2f(a.y) + w.y * bf2f(b.y);
        o.z += w.x * bf2f(a.z) + w.y * bf2f(b.z);
        o.w += w.x * bf2f(a.w) + w.y * bf2f(b.w);
    }
    *(float4*)&y[(size_t)token * DMODEL + c] = o;
}

// ---------------- Fallback GEMMs (round-0 proven, fp32 inline-convert) ----------------
__global__ __launch_bounds__(256) void gemm1_fb_kernel(
        const float* __restrict__ X, const float* __restrict__ WG, short* __restrict__ Hid)
{
    __shared__ short As[128][72];
    __shared__ short Bs[128][72];
    const int t = threadIdx.x;
    const int wave = t >> 6, lane = t & 63;
    const int m0 = blockIdx.y * 128, n0 = blockIdx.x * 128;
    const int wm = (wave >> 1) * 64, wn = (wave & 1) * 64;
    const int lm = lane & 15, lq = lane >> 4, lk = lq * 8;
    const int r0 = t >> 3, c8 = (t & 7) * 8;

    f32x4 acc[4][4];
#pragma unroll
    for (int a = 0; a < 4; a++)
#pragma unroll
        for (int b = 0; b < 4; b++) acc[a][b] = (f32x4)(0.f);

    for (int k0 = 0; k0 < DMODEL; k0 += 64) {
#pragma unroll
        for (int i = 0; i < 4; i++) {
            const int row = r0 + i * 32;
            const float* ga = X + (size_t)(m0 + row) * DMODEL + k0 + c8;
            float4 v0 = ((const float4*)ga)[0];
            float4 v1 = ((const float4*)ga)[1];
            short8 s = { f2bf(v0.x), f2bf(v0.y), f2bf(v0.z), f2bf(v0.w),
                         f2bf(v1.x), f2bf(v1.y), f2bf(v1.z), f2bf(v1.w) };
            *(short8*)&As[row][c8] = s;
            const float* gb = WG + (size_t)(n0 + row) * DMODEL + k0 + c8;
            float4 w0 = ((const float4*)gb)[0];
            float4 w1 = ((const float4*)gb)[1];
            short8 sw = { f2bf(w0.x), f2bf(w0.y), f2bf(w0.z), f2bf(w0.w),
                          f2bf(w1.x), f2bf(w1.y), f2bf(w1.z), f2bf(w1.w) };
            *(short8*)&Bs[row][c8] = sw;
        }
        __syncthreads();
#pragma unroll
        for (int kk = 0; kk < 64; kk += 32) {
            short8 af[4], bf[4];
#pragma unroll
            for (int mi = 0; mi < 4; mi++) af[mi] = *(const short8*)&As[wm + mi * 16 + lm][kk + lk];
#pragma unroll
            for (int ni = 0; ni < 4; ni++) bf[ni] = *(const short8*)&Bs[wn + ni * 16 + lm][kk + lk];
#pragma unroll
            for (int mi = 0; mi < 4; mi++)
#pragma unroll
                for (int ni = 0; ni < 4; ni++)
                    acc[mi][ni] = __builtin_amdgcn_mfma_f32_16x16x32_bf16(af[mi], bf[ni], acc[mi][ni], 0, 0, 0);
        }
        __syncthreads();
    }
#pragma unroll
    for (int mi = 0; mi < 4; mi++)
#pragma unroll
        for (int i = 0; i < 4; i++) {
            const int row = m0 + wm + mi * 16 + lq * 4 + i;
#pragma unroll
            for (int ni = 0; ni < 4; ni++) {
                const int col = n0 + wn + ni * 16 + lm;
                const float v = acc[mi][ni][i];
                const float s = v / (1.f + __expf(-v));
                Hid[(size_t)row * DHID + col] = f2bf(s);
            }
        }
}

__global__ __launch_bounds__(256) void gemm2_fb_kernel(
        const short* __restrict__ Hid, const float* __restrict__ WD,
        const int* __restrict__ gtok, const float* __restrict__ gw,
        const int* __restrict__ gcnt, float* __restrict__ Y)
{
    __shared__ short As[128][72];
    __shared__ short Bs[128][72];
    __shared__ int   tok_s[128];
    __shared__ float w_s[128];
    const int e = blockIdx.z;
    const int cnt = gcnt[e];
    const int m0 = blockIdx.y * 128;
    if (m0 >= cnt) return;
    const int n0 = blockIdx.x * 128;
    const int t = threadIdx.x;
    const int wave = t >> 6, lane = t & 63;
    const int wm = (wave >> 1) * 64, wn = (wave & 1) * 64;
    const int lm = lane & 15, lq = lane >> 4, lk = lq * 8;
    const int r0 = t >> 3, c8 = (t & 7) * 8;
    const float* WDe = WD + (size_t)e * DMODEL * DHID;

    if (t < 128) {
        const int r = m0 + t;
        const bool v = r < cnt;
        tok_s[t] = v ? gtok[e * CAP + r] : 0;
        w_s[t]   = v ? gw[e * CAP + r] : 0.f;
    }
    __syncthreads();

    f32x4 acc[4][4];
#pragma unroll
    for (int a = 0; a < 4; a++)
#pragma unroll
        for (int b = 0; b < 4; b++) acc[a][b] = (f32x4)(0.f);

    const int tokA[4] = { tok_s[r0], tok_s[r0 + 32], tok_s[r0 + 64], tok_s[r0 + 96] };

    for (int k0 = 0; k0 < DHID; k0 += 64) {
#pragma unroll
        for (int i = 0; i < 4; i++) {
            const int row = r0 + i * 32;
            uint4 av = *(const uint4*)(Hid + (size_t)tokA[i] * DHID + k0 + c8);
            *(uint4*)&As[row][c8] = av;
            const float* gb = WDe + (size_t)(n0 + row) * DHID + k0 + c8;
            float4 w0 = ((const float4*)gb)[0];
            float4 w1 = ((const float4*)gb)[1];
            short8 sw = { f2bf(w0.x), f2bf(w0.y), f2bf(w0.z), f2bf(w0.w),
                          f2bf(w1.x), f2bf(w1.y), f2bf(w1.z), f2bf(w1.w) };
            *(short8*)&Bs[row][c8] = sw;
        }
        __syncthreads();
#pragma unroll
        for (int kk = 0; kk < 64; kk += 32) {
            short8 af[4], bf[4];
#pragma unroll
            for (int mi = 0; mi < 4; mi++) af[mi] = *(const short8*)&As[wm + mi * 16 + lm][kk + lk];
#pragma unroll
            for (int ni = 0; ni < 4; ni++) bf[ni] = *(const short8*)&Bs[wn + ni * 16 + lm][kk + lk];
#pragma unroll
            for (int mi = 0; mi < 4; mi++)
#pragma unroll
                for (int ni = 0; ni < 4; ni++)
                    acc[mi][ni] = __builtin_amdgcn_mfma_f32_16x16x32_bf16(af[mi], bf[ni], acc[mi][ni], 0, 0, 0);
        }
        __syncthreads();
    }
#pragma unroll
    for (int mi = 0; mi < 4; mi++)
#pragma unroll
        for (int i = 0; i < 4; i++) {
            const int r = wm + mi * 16 + lq * 4 + i;
            const float wr = w_s[r];
            if (wr > 0.f) {
                const int token = tok_s[r];
#pragma unroll
                for (int ni = 0; ni < 4; ni++) {
                    const int col = n0 + wn + ni * 16 + lm;
                    atomicAdd(&Y[(size_t)token * DMODEL + col], acc[mi][ni][i] * wr);
                }
            }
        }
}

extern "C" void kernel_launch(void* const* d_in, const int* in_sizes, int n_in,
                              void* d_out, int out_size, void* d_ws, size_t ws_size,
                              hipStream_t stream) {
    const float* x  = (const float*)d_in[0];
    const float* wr = (const float*)d_in[1];
    const float* wg = (const float*)d_in[2];
    const float* wd = (const float*)d_in[3];
    float* y = (float*)d_out;

    char* w = (char*)d_ws;
    int2*   topk_idx  = (int2*)w;    w += NTOK * sizeof(int2);
    float2* topk_gate = (float2*)w;  w += NTOK * sizeof(float2);
    int*    gtok      = (int*)w;     w += NEXP * CAP * sizeof(int);
    float*  gw        = (float*)w;   w += NEXP * CAP * sizeof(float);
    int*    gcnt      = (int*)w;     w += 256;
    int2*   tslot     = (int2*)w;    w += NTOK * sizeof(int2);
    float2* tw        = (float2*)w;  w += NTOK * sizeof(float2);
    short*  Hid       = (short*)w;   w += (size_t)NTOK * DHID * sizeof(short);
    short*  WDb       = (short*)w;   w += (size_t)NEXP * DMODEL * DHID * sizeof(short);
    // Xb (8 MB) + WGb (4 MB) die after gemm1; Yp (KS*5120*1024 bf16) aliases that
    // span (extended past it at KS=4, same 96 MB budget R6 proved to fit).
    short*  Xb        = (short*)w;
    short*  WGb       = (short*)(w + (size_t)NTOK * DMODEL * sizeof(short));
    short*  Yp        = (short*)w;
    const size_t span12 = ((size_t)NTOK * DMODEL + (size_t)DHID * DMODEL) * sizeof(short);
    const size_t need63 = (size_t)(w - (char*)d_ws) + span12;                       // KS=1
    const size_t need96 = (size_t)(w - (char*)d_ws) + (size_t)4 * SLOTS * DMODEL * 2; // KS=4

    if (ws_size >= need63) {
        const int KS2 = (ws_size >= need96) ? 4 : 1;
        prep_kernel<<<(int)((NWG + NWD) / 2048), 256, 0, stream>>>(
            x, wr, Xb, topk_idx, topk_gate, wg, WGb, wd, WDb);
        scan_kernel<<<1, 1024, 0, stream>>>(topk_idx, topk_gate, gtok, gw, gcnt, tslot, tw);
        gemm1_kernel<<<dim3(DHID / 128, NTOK / 128), 256, 0, stream>>>(Xb, WGb, Hid);
        gemm2_kernel<<<dim3(NEXP, DMODEL / 128, (CAP / 128) * KS2), 256, 0, stream>>>(
            Hid, WDb, gtok, gcnt, Yp, KS2);
        combine_kernel<<<NTOK, 256, 0, stream>>>(Yp, tslot, tw, y, KS2);
    } else {
        hipMemsetAsync(y, 0, (size_t)NTOK * DMODEL * sizeof(float), stream);
        router_fb_kernel<<<NTOK / 4, 256, 0, stream>>>(x, wr, topk_idx, topk_gate);
        scan_kernel<<<1, 1024, 0, stream>>>(topk_idx, topk_gate, gtok, gw, gcnt, tslot, tw);
        gemm1_fb_kernel<<<dim3(DHID / 128, NTOK / 128), 256, 0, stream>>>(x, wg, Hid);
        gemm2_fb_kernel<<<dim3(DMODEL / 128, (CAP + 127) / 128, NEXP), 256, 0, stream>>>(
            Hid, wd, gtok, gw, gcnt, y);
    }
}